// Round 1
// baseline (950.772 us; speedup 1.0000x reference)
//
#include <hip/hip_runtime.h>

// Problem dims
#define B_DIM 64
#define IN_CH 16
#define H_DIM 256
#define FDIM  128
#define NF    1001
#define INS0  144      // FDIM + IN_CH
#define TB    7        // timesteps per block in gf_kernel (1001 = 7*143)

// ---------------------------------------------------------------------------
// Fast activations: raw v_exp_f32 (2^x) + v_rcp_f32. ~1ulp each; dynamics are
// contractive (sigmoid(f) < 1) so error does not accumulate. Threshold 2.8e-4.
// ---------------------------------------------------------------------------
__device__ __forceinline__ float fast_sigmoid(float x) {
    float e = __builtin_amdgcn_exp2f(-1.44269504088896340736f * x);
    return __builtin_amdgcn_rcpf(1.0f + e);
}
__device__ __forceinline__ float fast_tanh(float x) {
    // tanh(x) = 1 - 2/(exp(2x)+1); exp(2x) = 2^(2*log2e*x)
    float e = __builtin_amdgcn_exp2f(2.88539008177792681472f * x);
    return 1.0f - 2.0f * __builtin_amdgcn_rcpf(e + 1.0f);
}

// ---------------------------------------------------------------------------
// Wave64 sum-reduce via DPP (VALU-rate, avoids 6x ds_swizzle LDS latency):
// row_shr 1/2/4/8 accumulate within 16-lane rows; row_bcast:15 (rows 1,3) and
// row_bcast:31 (rows 2,3) combine rows; total lands in lane 63; readlane
// broadcasts to an SGPR.
// ---------------------------------------------------------------------------
template<int CTRL, int ROW_MASK>
__device__ __forceinline__ float dpp_add(float x) {
    int y = __builtin_amdgcn_update_dpp(0, __float_as_int(x), CTRL, ROW_MASK, 0xf, true);
    return x + __int_as_float(y);
}
__device__ __forceinline__ float wave_allreduce(float x) {
    x = dpp_add<0x111, 0xf>(x);   // row_shr:1
    x = dpp_add<0x112, 0xf>(x);   // row_shr:2
    x = dpp_add<0x114, 0xf>(x);   // row_shr:4
    x = dpp_add<0x118, 0xf>(x);   // row_shr:8
    x = dpp_add<0x142, 0xa>(x);   // row_bcast:15 into rows 1,3
    x = dpp_add<0x143, 0xc>(x);   // row_bcast:31 into rows 2,3
    return __int_as_float(__builtin_amdgcn_readlane(__float_as_int(x), 63));
}

// ---------------------------------------------------------------------------
// Gf[t][j] = sum_k f[t][k] * Wih0[j][k], k<128 (batch-independent gate bases).
// 143 blocks x 1024 threads, TB=7 timesteps per block; f rows staged in LDS
// (broadcast reads), Wih0 rows read as float4 (row byte offset j*576, 16B ok).
// ---------------------------------------------------------------------------
__global__ __launch_bounds__(1024) void gf_kernel(
    const float* __restrict__ f, const float* __restrict__ W,
    float* __restrict__ Gf)
{
    __shared__ float fs[TB][FDIM];
    const int t0 = blockIdx.x * TB;
    const int tid = threadIdx.x;
    for (int i = tid; i < TB * FDIM; i += 1024)
        fs[i >> 7][i & 127] = f[t0 * FDIM + i];
    __syncthreads();

    const int j = tid;
    const float4* w4 = (const float4*)(W + j * INS0);
    float acc[TB];
#pragma unroll
    for (int t = 0; t < TB; ++t) acc[t] = 0.f;
#pragma unroll
    for (int kc = 0; kc < 8; ++kc) {
        float4 a = w4[kc * 4 + 0];
        float4 b = w4[kc * 4 + 1];
        float4 c = w4[kc * 4 + 2];
        float4 d = w4[kc * 4 + 3];
#pragma unroll
        for (int t = 0; t < TB; ++t) {
            const float* fp = &fs[t][kc * 16];
            float s = acc[t];
            s = fmaf(a.x, fp[0], s);  s = fmaf(a.y, fp[1], s);
            s = fmaf(a.z, fp[2], s);  s = fmaf(a.w, fp[3], s);
            s = fmaf(b.x, fp[4], s);  s = fmaf(b.y, fp[5], s);
            s = fmaf(b.z, fp[6], s);  s = fmaf(b.w, fp[7], s);
            s = fmaf(c.x, fp[8], s);  s = fmaf(c.y, fp[9], s);
            s = fmaf(c.z, fp[10], s); s = fmaf(c.w, fp[11], s);
            s = fmaf(d.x, fp[12], s); s = fmaf(d.y, fp[13], s);
            s = fmaf(d.z, fp[14], s); s = fmaf(d.w, fp[15], s);
            acc[t] = s;
        }
    }
#pragma unroll
    for (int t = 0; t < TB; ++t)
        Gf[(size_t)(t0 + t) * 1024 + j] = acc[t];
}

// ---------------------------------------------------------------------------
// Gxb[b][j] = sum_k x[b][k] * Wih0[j][128+k] + bih0[j] + bhh0[j]  (t-invariant)
// ---------------------------------------------------------------------------
__global__ __launch_bounds__(1024) void gxb_kernel(
    const float* __restrict__ x, const float* __restrict__ W,
    const float* __restrict__ bih, const float* __restrict__ bhh,
    float* __restrict__ Gxb)
{
    const int b = blockIdx.x;
    const int j = threadIdx.x;
    const float* w = W + j * INS0 + FDIM;
    const float* xb = x + b * IN_CH;
    float s = bih[j] + bhh[j];
#pragma unroll
    for (int k = 0; k < IN_CH; ++k) s = fmaf(xb[k], w[k], s);
    Gxb[b * 1024 + j] = s;
}

// ---------------------------------------------------------------------------
// Main recurrence. grid = 64 (one block per batch), block = 192 (3 waves).
// Wave l == layer l, software-pipelined: at iteration k wave l processes
// timestep t = k - l. Scalar h handoff through double-buffered LDS slots,
// one __syncthreads per iteration. Lane owns hidden j = lane*4..lane*4+3 for
// all 4 gates (gate g at flat index g*256 + j). c stays in registers.
// Gf row for t+1 is register-prefetched one full iteration ahead.
// ---------------------------------------------------------------------------
__global__ __launch_bounds__(192) void lstm_pipeline(
    const float* __restrict__ Gf, const float* __restrict__ Gxb,
    const float* __restrict__ Whh0, const float* __restrict__ Whr0,
    const float* __restrict__ Wih1, const float* __restrict__ Whh1,
    const float* __restrict__ bih1, const float* __restrict__ bhh1,
    const float* __restrict__ Whr1,
    const float* __restrict__ Wih2, const float* __restrict__ Whh2,
    const float* __restrict__ bih2, const float* __restrict__ bhh2,
    const float* __restrict__ Whr2,
    float* __restrict__ out)
{
    const int b    = blockIdx.x;
    const int wave = threadIdx.x >> 6;
    const int lane = threadIdx.x & 63;
    const int jb   = lane * 4;

    __shared__ float hsl[3][2];   // [layer][parity] scalar h handoff

    float base[16];   // wave0: Gf-complement (Gxb incl. biases); wave1/2: bih+bhh
    float wih[16];    // wave1/2: W_ih column (input-scalar weight)
    float whh[16];    // recurrent column
    float whr[4];     // projection row slice

    const float *whh_p, *whr_p;
    if (wave == 0)      { whh_p = Whh0; whr_p = Whr0; }
    else if (wave == 1) { whh_p = Whh1; whr_p = Whr1; }
    else                { whh_p = Whh2; whr_p = Whr2; }

#pragma unroll
    for (int g = 0; g < 4; ++g) {
        float4 w = *(const float4*)(whh_p + g * 256 + jb);
        whh[g*4+0] = w.x; whh[g*4+1] = w.y; whh[g*4+2] = w.z; whh[g*4+3] = w.w;
    }
    {
        float4 w = *(const float4*)(whr_p + jb);
        whr[0] = w.x; whr[1] = w.y; whr[2] = w.z; whr[3] = w.w;
    }

    if (wave == 0) {
#pragma unroll
        for (int g = 0; g < 4; ++g) {
            float4 v = *(const float4*)(Gxb + b * 1024 + g * 256 + jb);
            base[g*4+0] = v.x; base[g*4+1] = v.y; base[g*4+2] = v.z; base[g*4+3] = v.w;
            wih[g*4+0] = 0.f; wih[g*4+1] = 0.f; wih[g*4+2] = 0.f; wih[g*4+3] = 0.f;
        }
    } else {
        const float* bi = (wave == 1) ? bih1 : bih2;
        const float* bh = (wave == 1) ? bhh1 : bhh2;
        const float* wi = (wave == 1) ? Wih1 : Wih2;
#pragma unroll
        for (int g = 0; g < 4; ++g) {
            float4 v1 = *(const float4*)(bi + g * 256 + jb);
            float4 v2 = *(const float4*)(bh + g * 256 + jb);
            float4 v3 = *(const float4*)(wi + g * 256 + jb);
            base[g*4+0] = v1.x + v2.x; base[g*4+1] = v1.y + v2.y;
            base[g*4+2] = v1.z + v2.z; base[g*4+3] = v1.w + v2.w;
            wih[g*4+0] = v3.x; wih[g*4+1] = v3.y; wih[g*4+2] = v3.z; wih[g*4+3] = v3.w;
        }
    }

    float c4[4] = {0.f, 0.f, 0.f, 0.f};
    float h_state = 0.f;

    float4 gfn[4];  // prefetched Gf row (wave 0 only)
    if (wave == 0) {
#pragma unroll
        for (int g = 0; g < 4; ++g)
            gfn[g] = *(const float4*)(Gf + g * 256 + jb);
    }

    for (int k = 0; k < NF + 2; ++k) {
        __syncthreads();
        const int t = k - wave;
        const bool active = (t >= 0) && (t < NF);

        float h_in = 0.f;
        if (wave > 0 && active) h_in = hsl[wave - 1][(k - 1) & 1];

        float gcur[16];
        if (wave == 0) {
#pragma unroll
            for (int g = 0; g < 4; ++g) {
                gcur[g*4+0] = gfn[g].x; gcur[g*4+1] = gfn[g].y;
                gcur[g*4+2] = gfn[g].z; gcur[g*4+3] = gfn[g].w;
            }
            if (k + 1 < NF) {
                const float* p = Gf + (size_t)(k + 1) * 1024;
#pragma unroll
                for (int g = 0; g < 4; ++g)
                    gfn[g] = *(const float4*)(p + g * 256 + jb);
            }
        }

        if (active) {
            float contrib = 0.f;
#pragma unroll
            for (int jj = 0; jj < 4; ++jj) {
                float gi, gf_, gg, go;
                if (wave == 0) {
                    gi  = fmaf(h_state, whh[0*4+jj], gcur[0*4+jj] + base[0*4+jj]);
                    gf_ = fmaf(h_state, whh[1*4+jj], gcur[1*4+jj] + base[1*4+jj]);
                    gg  = fmaf(h_state, whh[2*4+jj], gcur[2*4+jj] + base[2*4+jj]);
                    go  = fmaf(h_state, whh[3*4+jj], gcur[3*4+jj] + base[3*4+jj]);
                } else {
                    gi  = fmaf(h_state, whh[0*4+jj], fmaf(h_in, wih[0*4+jj], base[0*4+jj]));
                    gf_ = fmaf(h_state, whh[1*4+jj], fmaf(h_in, wih[1*4+jj], base[1*4+jj]));
                    gg  = fmaf(h_state, whh[2*4+jj], fmaf(h_in, wih[2*4+jj], base[2*4+jj]));
                    go  = fmaf(h_state, whh[3*4+jj], fmaf(h_in, wih[3*4+jj], base[3*4+jj]));
                }
                float si = fast_sigmoid(gi);
                float sf = fast_sigmoid(gf_);
                float tg = fast_tanh(gg);
                float so = fast_sigmoid(go);
                float c  = fmaf(sf, c4[jj], si * tg);
                c4[jj] = c;
                float hr = so * fast_tanh(c);
                contrib = fmaf(hr, whr[jj], contrib);
            }
            float tot = wave_allreduce(contrib);
            h_state = tot;
            if (lane == 0) hsl[wave][k & 1] = tot;
            if (wave == 2 && lane == 0) out[(size_t)b * NF + t] = tot;
        }
    }
}

// ---------------------------------------------------------------------------
extern "C" void kernel_launch(void* const* d_in, const int* in_sizes, int n_in,
                              void* d_out, int out_size, void* d_ws, size_t ws_size,
                              hipStream_t stream)
{
    const float* x    = (const float*)d_in[0];
    const float* f    = (const float*)d_in[1];
    const float* Wih0 = (const float*)d_in[2];
    const float* Whh0 = (const float*)d_in[3];
    const float* bih0 = (const float*)d_in[4];
    const float* bhh0 = (const float*)d_in[5];
    const float* Whr0 = (const float*)d_in[6];
    const float* Wih1 = (const float*)d_in[7];
    const float* Whh1 = (const float*)d_in[8];
    const float* bih1 = (const float*)d_in[9];
    const float* bhh1 = (const float*)d_in[10];
    const float* Whr1 = (const float*)d_in[11];
    const float* Wih2 = (const float*)d_in[12];
    const float* Whh2 = (const float*)d_in[13];
    const float* bih2 = (const float*)d_in[14];
    const float* bhh2 = (const float*)d_in[15];
    const float* Whr2 = (const float*)d_in[16];
    float* out = (float*)d_out;

    float* Gf  = (float*)d_ws;                       // NF * 1024 floats (4.1 MB)
    float* Gxb = Gf + (size_t)NF * 1024;             // 64 * 1024 floats

    gf_kernel<<<143, 1024, 0, stream>>>(f, Wih0, Gf);
    gxb_kernel<<<64, 1024, 0, stream>>>(x, Wih0, bih0, bhh0, Gxb);
    lstm_pipeline<<<64, 192, 0, stream>>>(Gf, Gxb, Whh0, Whr0,
                                          Wih1, Whh1, bih1, bhh1, Whr1,
                                          Wih2, Whh2, bih2, bhh2, Whr2,
                                          out);
}

// Round 3
// 546.604 us; speedup vs baseline: 1.7394x; 1.7394x over previous
//
#include <hip/hip_runtime.h>

// Problem dims
#define B_DIM 64
#define IN_CH 16
#define H_DIM 256
#define FDIM  128
#define NF    1001
#define INS0  144      // FDIM + IN_CH
#define TB    7        // timesteps per block in gf_kernel (1001 = 7*143)
#define U     7        // timesteps per pipeline epoch (1001 = 7*143, exact)
#define NEPOCH 143

// ---------------------------------------------------------------------------
// Fast activations: raw v_exp_f32 (2^x) + v_rcp_f32. ~1ulp each; dynamics are
// contractive so error does not accumulate (measured absmax 6e-5 vs 2.8e-4).
// ---------------------------------------------------------------------------
__device__ __forceinline__ float fast_sigmoid(float x) {
    float e = __builtin_amdgcn_exp2f(-1.44269504088896340736f * x);
    return __builtin_amdgcn_rcpf(1.0f + e);
}
__device__ __forceinline__ float fast_tanh(float x) {
    float e = __builtin_amdgcn_exp2f(2.88539008177792681472f * x);
    return 1.0f - 2.0f * __builtin_amdgcn_rcpf(e + 1.0f);
}

// ---------------------------------------------------------------------------
// Wave64 sum-reduce via DPP (VALU-rate, no LDS latency). Result broadcast via
// readlane 63 -> SGPR.
// ---------------------------------------------------------------------------
template<int CTRL, int ROW_MASK>
__device__ __forceinline__ float dpp_add(float x) {
    int y = __builtin_amdgcn_update_dpp(0, __float_as_int(x), CTRL, ROW_MASK, 0xf, true);
    return x + __int_as_float(y);
}
__device__ __forceinline__ float wave_allreduce(float x) {
    x = dpp_add<0x111, 0xf>(x);   // row_shr:1
    x = dpp_add<0x112, 0xf>(x);   // row_shr:2
    x = dpp_add<0x114, 0xf>(x);   // row_shr:4
    x = dpp_add<0x118, 0xf>(x);   // row_shr:8
    x = dpp_add<0x142, 0xa>(x);   // row_bcast:15 into rows 1,3
    x = dpp_add<0x143, 0xc>(x);   // row_bcast:31 into rows 2,3
    return __int_as_float(__builtin_amdgcn_readlane(__float_as_int(x), 63));
}

// ---------------------------------------------------------------------------
// Gf[t][j] = sum_k f[t][k] * Wih0[j][k], k<128 (batch-independent gate bases).
// ---------------------------------------------------------------------------
__global__ __launch_bounds__(1024) void gf_kernel(
    const float* __restrict__ f, const float* __restrict__ W,
    float* __restrict__ Gf)
{
    __shared__ float fs[TB][FDIM];
    const int t0 = blockIdx.x * TB;
    const int tid = threadIdx.x;
    for (int i = tid; i < TB * FDIM; i += 1024)
        fs[i >> 7][i & 127] = f[t0 * FDIM + i];
    __syncthreads();

    const int j = tid;
    const float4* w4 = (const float4*)(W + j * INS0);
    float acc[TB];
#pragma unroll
    for (int t = 0; t < TB; ++t) acc[t] = 0.f;
#pragma unroll
    for (int kc = 0; kc < 8; ++kc) {
        float4 a = w4[kc * 4 + 0];
        float4 b = w4[kc * 4 + 1];
        float4 c = w4[kc * 4 + 2];
        float4 d = w4[kc * 4 + 3];
#pragma unroll
        for (int t = 0; t < TB; ++t) {
            const float* fp = &fs[t][kc * 16];
            float s = acc[t];
            s = fmaf(a.x, fp[0], s);  s = fmaf(a.y, fp[1], s);
            s = fmaf(a.z, fp[2], s);  s = fmaf(a.w, fp[3], s);
            s = fmaf(b.x, fp[4], s);  s = fmaf(b.y, fp[5], s);
            s = fmaf(b.z, fp[6], s);  s = fmaf(b.w, fp[7], s);
            s = fmaf(c.x, fp[8], s);  s = fmaf(c.y, fp[9], s);
            s = fmaf(c.z, fp[10], s); s = fmaf(c.w, fp[11], s);
            s = fmaf(d.x, fp[12], s); s = fmaf(d.y, fp[13], s);
            s = fmaf(d.z, fp[14], s); s = fmaf(d.w, fp[15], s);
            acc[t] = s;
        }
    }
#pragma unroll
    for (int t = 0; t < TB; ++t)
        Gf[(size_t)(t0 + t) * 1024 + j] = acc[t];
}

// ---------------------------------------------------------------------------
// Gxb[b][j] = sum_k x[b][k] * Wih0[j][128+k] + bih0[j] + bhh0[j]  (t-invariant)
// ---------------------------------------------------------------------------
__global__ __launch_bounds__(1024) void gxb_kernel(
    const float* __restrict__ x, const float* __restrict__ W,
    const float* __restrict__ bih, const float* __restrict__ bhh,
    float* __restrict__ Gxb)
{
    const int b = blockIdx.x;
    const int j = threadIdx.x;
    const float* w = W + j * INS0 + FDIM;
    const float* xb = x + b * IN_CH;
    float s = bih[j] + bhh[j];
#pragma unroll
    for (int k = 0; k < IN_CH; ++k) s = fmaf(xb[k], w[k], s);
    Gxb[b * 1024 + j] = s;
}

// ---------------------------------------------------------------------------
// Main recurrence, epoch-pipelined. grid = 64 (block = batch), block = 192
// (3 waves, wave l = layer l). Epoch e: wave l processes the U=7 timesteps
// of its epoch te = e - l, consuming the 7 h-values wave l-1 produced in
// epoch e-1 (double-buffered LDS, ONE __syncthreads per epoch -> 145 barriers
// instead of 1003). Per-step critical chain is compute-only:
//   fmaf(h,whh,pre[u]) -> sigmoid/tanh -> c -> tanh(c) -> dot -> DPP reduce.
// pre[u] (input+bias contribution) depends only on epoch-start data and is
// hoisted off the h-chain. Wave 0 loads its 7 Gf rows at epoch start (L2-hit).
// ---------------------------------------------------------------------------
__global__ __launch_bounds__(192) void lstm_pipeline(
    const float* __restrict__ Gf, const float* __restrict__ Gxb,
    const float* __restrict__ Whh0, const float* __restrict__ Whr0,
    const float* __restrict__ Wih1, const float* __restrict__ Whh1,
    const float* __restrict__ bih1, const float* __restrict__ bhh1,
    const float* __restrict__ Whr1,
    const float* __restrict__ Wih2, const float* __restrict__ Whh2,
    const float* __restrict__ bih2, const float* __restrict__ bhh2,
    const float* __restrict__ Whr2,
    float* __restrict__ out)
{
    const int b    = blockIdx.x;
    const int wave = threadIdx.x >> 6;
    const int lane = threadIdx.x & 63;
    const int jb   = lane * 4;

    __shared__ float hbuf[3][2][U];   // [layer][parity][step-in-epoch]

    float base[16];   // wave0: Gxb incl. biases; wave1/2: bih+bhh
    float wih[16];    // wave1/2: W_ih column (scalar-input weight)
    float whh[16];    // recurrent column
    float whr[4];     // projection row slice

    const float *whh_p, *whr_p;
    if (wave == 0)      { whh_p = Whh0; whr_p = Whr0; }
    else if (wave == 1) { whh_p = Whh1; whr_p = Whr1; }
    else                { whh_p = Whh2; whr_p = Whr2; }

#pragma unroll
    for (int g = 0; g < 4; ++g) {
        float4 w = *(const float4*)(whh_p + g * 256 + jb);
        whh[g*4+0] = w.x; whh[g*4+1] = w.y; whh[g*4+2] = w.z; whh[g*4+3] = w.w;
    }
    {
        float4 w = *(const float4*)(whr_p + jb);
        whr[0] = w.x; whr[1] = w.y; whr[2] = w.z; whr[3] = w.w;
    }

    if (wave == 0) {
#pragma unroll
        for (int g = 0; g < 4; ++g) {
            float4 v = *(const float4*)(Gxb + b * 1024 + g * 256 + jb);
            base[g*4+0] = v.x; base[g*4+1] = v.y; base[g*4+2] = v.z; base[g*4+3] = v.w;
            wih[g*4+0] = 0.f; wih[g*4+1] = 0.f; wih[g*4+2] = 0.f; wih[g*4+3] = 0.f;
        }
    } else {
        const float* bi = (wave == 1) ? bih1 : bih2;
        const float* bh = (wave == 1) ? bhh1 : bhh2;
        const float* wi = (wave == 1) ? Wih1 : Wih2;
#pragma unroll
        for (int g = 0; g < 4; ++g) {
            float4 v1 = *(const float4*)(bi + g * 256 + jb);
            float4 v2 = *(const float4*)(bh + g * 256 + jb);
            float4 v3 = *(const float4*)(wi + g * 256 + jb);
            base[g*4+0] = v1.x + v2.x; base[g*4+1] = v1.y + v2.y;
            base[g*4+2] = v1.z + v2.z; base[g*4+3] = v1.w + v2.w;
            wih[g*4+0] = v3.x; wih[g*4+1] = v3.y; wih[g*4+2] = v3.z; wih[g*4+3] = v3.w;
        }
    }

    float c4[4] = {0.f, 0.f, 0.f, 0.f};
    float h_state = 0.f;

    for (int e = 0; e < NEPOCH + 2; ++e) {
        __syncthreads();
        const int te = e - wave;                  // this wave's epoch index
        const bool active = (te >= 0) && (te < NEPOCH);

        // pre[u][i]: full h-independent gate contribution for each step
        float pre[U][16];

        if (active) {
            if (wave == 0) {
                const float* p = Gf + (size_t)te * U * 1024;
#pragma unroll
                for (int u = 0; u < U; ++u) {
#pragma unroll
                    for (int g = 0; g < 4; ++g) {
                        float4 v = *(const float4*)(p + u * 1024 + g * 256 + jb);
                        pre[u][g*4+0] = v.x + base[g*4+0];
                        pre[u][g*4+1] = v.y + base[g*4+1];
                        pre[u][g*4+2] = v.z + base[g*4+2];
                        pre[u][g*4+3] = v.w + base[g*4+3];
                    }
                }
            } else {
                const int par = (e - 1) & 1;
#pragma unroll
                for (int u = 0; u < U; ++u) {
                    float hin = hbuf[wave - 1][par][u];
#pragma unroll
                    for (int i = 0; i < 16; ++i)
                        pre[u][i] = fmaf(hin, wih[i], base[i]);
                }
            }

#pragma unroll
            for (int u = 0; u < U; ++u) {
                float contrib = 0.f;
#pragma unroll
                for (int jj = 0; jj < 4; ++jj) {
                    float gi  = fmaf(h_state, whh[0*4+jj], pre[u][0*4+jj]);
                    float gf_ = fmaf(h_state, whh[1*4+jj], pre[u][1*4+jj]);
                    float gg  = fmaf(h_state, whh[2*4+jj], pre[u][2*4+jj]);
                    float go  = fmaf(h_state, whh[3*4+jj], pre[u][3*4+jj]);
                    float si = fast_sigmoid(gi);
                    float sf = fast_sigmoid(gf_);
                    float tg = fast_tanh(gg);
                    float so = fast_sigmoid(go);
                    float c  = fmaf(sf, c4[jj], si * tg);
                    c4[jj] = c;
                    float hr = so * fast_tanh(c);
                    contrib = fmaf(hr, whr[jj], contrib);
                }
                float tot = wave_allreduce(contrib);
                h_state = tot;
                if (lane == 0) hbuf[wave][e & 1][u] = tot;
                if (wave == 2 && lane == 0)
                    out[(size_t)b * NF + te * U + u] = tot;
            }
        }
    }
}

// ---------------------------------------------------------------------------
extern "C" void kernel_launch(void* const* d_in, const int* in_sizes, int n_in,
                              void* d_out, int out_size, void* d_ws, size_t ws_size,
                              hipStream_t stream)
{
    const float* x    = (const float*)d_in[0];
    const float* f    = (const float*)d_in[1];
    const float* Wih0 = (const float*)d_in[2];
    const float* Whh0 = (const float*)d_in[3];
    const float* bih0 = (const float*)d_in[4];
    const float* bhh0 = (const float*)d_in[5];
    const float* Whr0 = (const float*)d_in[6];
    const float* Wih1 = (const float*)d_in[7];
    const float* Whh1 = (const float*)d_in[8];
    const float* bih1 = (const float*)d_in[9];
    const float* bhh1 = (const float*)d_in[10];
    const float* Whr1 = (const float*)d_in[11];
    const float* Wih2 = (const float*)d_in[12];
    const float* Whh2 = (const float*)d_in[13];
    const float* bih2 = (const float*)d_in[14];
    const float* bhh2 = (const float*)d_in[15];
    const float* Whr2 = (const float*)d_in[16];
    float* out = (float*)d_out;

    float* Gf  = (float*)d_ws;                       // NF * 1024 floats (4.1 MB)
    float* Gxb = Gf + (size_t)NF * 1024;             // 64 * 1024 floats

    gf_kernel<<<143, 1024, 0, stream>>>(f, Wih0, Gf);
    gxb_kernel<<<64, 1024, 0, stream>>>(x, Wih0, bih0, bhh0, Gxb);
    lstm_pipeline<<<64, 192, 0, stream>>>(Gf, Gxb, Whh0, Whr0,
                                          Wih1, Whh1, bih1, bhh1, Whr1,
                                          Wih2, Whh2, bih2, bhh2, Whr2,
                                          out);
}

// Round 4
// 487.975 us; speedup vs baseline: 1.9484x; 1.1201x over previous
//
#include <hip/hip_runtime.h>

// Problem dims
#define B_DIM 64
#define IN_CH 16
#define H_DIM 256
#define FDIM  128
#define NF    1001
#define INS0  144      // FDIM + IN_CH
#define TB    7        // timesteps per block in gf_kernel (1001 = 7*143)
#define U     7        // timesteps per pipeline epoch (1001 = 7*143, exact)
#define NEPOCH 143

// Gate pre-activations are PRE-SCALED so they feed v_exp_f32 (exp2) directly:
//   rows i,f,o:  scale = -log2(e)    -> exp2(arg) = e^{-gate}
//   row  g:      scale = -2*log2(e)  -> exp2(arg) = e^{-2*gate}
#define SC_IFO (-1.44269504088896340736f)
#define SC_G   (-2.88539008177792681472f)

__device__ __forceinline__ float gate_scale(int j) {
    // flat gate index j in [0,1024): rows 512..767 are the g gate
    return (j >= 512 && j < 768) ? SC_G : SC_IFO;
}

// ---------------------------------------------------------------------------
// Wave64 sum-reduce via DPP (VALU-rate). Result broadcast via readlane 63.
// ---------------------------------------------------------------------------
template<int CTRL, int ROW_MASK>
__device__ __forceinline__ float dpp_add(float x) {
    int y = __builtin_amdgcn_update_dpp(0, __float_as_int(x), CTRL, ROW_MASK, 0xf, true);
    return x + __int_as_float(y);
}
__device__ __forceinline__ float wave_allreduce(float x) {
    x = dpp_add<0x111, 0xf>(x);   // row_shr:1
    x = dpp_add<0x112, 0xf>(x);   // row_shr:2
    x = dpp_add<0x114, 0xf>(x);   // row_shr:4
    x = dpp_add<0x118, 0xf>(x);   // row_shr:8
    x = dpp_add<0x142, 0xa>(x);   // row_bcast:15 into rows 1,3
    x = dpp_add<0x143, 0xc>(x);   // row_bcast:31 into rows 2,3
    return __int_as_float(__builtin_amdgcn_readlane(__float_as_int(x), 63));
}

// ---------------------------------------------------------------------------
// Gf[t][j] = (sum_k f[t][k] * Wih0[j][k]) * gate_scale(j)   (batch-independent)
// ---------------------------------------------------------------------------
__global__ __launch_bounds__(1024) void gf_kernel(
    const float* __restrict__ f, const float* __restrict__ W,
    float* __restrict__ Gf)
{
    __shared__ float fs[TB][FDIM];
    const int t0 = blockIdx.x * TB;
    const int tid = threadIdx.x;
    for (int i = tid; i < TB * FDIM; i += 1024)
        fs[i >> 7][i & 127] = f[t0 * FDIM + i];
    __syncthreads();

    const int j = tid;
    const float4* w4 = (const float4*)(W + j * INS0);
    float acc[TB];
#pragma unroll
    for (int t = 0; t < TB; ++t) acc[t] = 0.f;
#pragma unroll
    for (int kc = 0; kc < 8; ++kc) {
        float4 a = w4[kc * 4 + 0];
        float4 b = w4[kc * 4 + 1];
        float4 c = w4[kc * 4 + 2];
        float4 d = w4[kc * 4 + 3];
#pragma unroll
        for (int t = 0; t < TB; ++t) {
            const float* fp = &fs[t][kc * 16];
            float s = acc[t];
            s = fmaf(a.x, fp[0], s);  s = fmaf(a.y, fp[1], s);
            s = fmaf(a.z, fp[2], s);  s = fmaf(a.w, fp[3], s);
            s = fmaf(b.x, fp[4], s);  s = fmaf(b.y, fp[5], s);
            s = fmaf(b.z, fp[6], s);  s = fmaf(b.w, fp[7], s);
            s = fmaf(c.x, fp[8], s);  s = fmaf(c.y, fp[9], s);
            s = fmaf(c.z, fp[10], s); s = fmaf(c.w, fp[11], s);
            s = fmaf(d.x, fp[12], s); s = fmaf(d.y, fp[13], s);
            s = fmaf(d.z, fp[14], s); s = fmaf(d.w, fp[15], s);
            acc[t] = s;
        }
    }
    const float sc = gate_scale(j);
#pragma unroll
    for (int t = 0; t < TB; ++t)
        Gf[(size_t)(t0 + t) * 1024 + j] = acc[t] * sc;
}

// ---------------------------------------------------------------------------
// Gxb[b][j] = (sum_k x[b][k]*Wih0[j][128+k] + bih0[j] + bhh0[j]) * gate_scale(j)
// ---------------------------------------------------------------------------
__global__ __launch_bounds__(1024) void gxb_kernel(
    const float* __restrict__ x, const float* __restrict__ W,
    const float* __restrict__ bih, const float* __restrict__ bhh,
    float* __restrict__ Gxb)
{
    const int b = blockIdx.x;
    const int j = threadIdx.x;
    const float* w = W + j * INS0 + FDIM;
    const float* xb = x + b * IN_CH;
    float s = bih[j] + bhh[j];
#pragma unroll
    for (int k = 0; k < IN_CH; ++k) s = fmaf(xb[k], w[k], s);
    Gxb[b * 1024 + j] = s * gate_scale(j);
}

// ---------------------------------------------------------------------------
// Main recurrence, epoch-pipelined (structure unchanged from the 447us
// version). Per-unit math now uses 5 exp + 2 rcp (shared reciprocals):
//   A=e^-gi B=e^-2gg D=e^-gf F=e^-go C=e^-2c
//   r1 = rcp((1+A)(1+B)(1+D)):  si*tg = (1-B)(1+D)r1 ; sf = (1+A)(1+B)r1
//   r2 = rcp((1+F)(1+C)):       hr    = (1-C)r2
// All gate pre-activations arrive pre-scaled for exp2.
// ---------------------------------------------------------------------------
__global__ __launch_bounds__(192) void lstm_pipeline(
    const float* __restrict__ Gf, const float* __restrict__ Gxb,
    const float* __restrict__ Whh0, const float* __restrict__ Whr0,
    const float* __restrict__ Wih1, const float* __restrict__ Whh1,
    const float* __restrict__ bih1, const float* __restrict__ bhh1,
    const float* __restrict__ Whr1,
    const float* __restrict__ Wih2, const float* __restrict__ Whh2,
    const float* __restrict__ bih2, const float* __restrict__ bhh2,
    const float* __restrict__ Whr2,
    float* __restrict__ out)
{
    const int b    = blockIdx.x;
    const int wave = threadIdx.x >> 6;
    const int lane = threadIdx.x & 63;
    const int jb   = lane * 4;

    __shared__ float hbuf[3][2][U];   // [layer][parity][step-in-epoch]

    float base[16];   // wave0: Gxb (pre-scaled); wave1/2: (bih+bhh)*scale
    float wih[16];    // wave1/2: W_ih column * scale
    float whh[16];    // recurrent column * scale
    float whr[4];     // projection row slice (unscaled)

    const float *whh_p, *whr_p;
    if (wave == 0)      { whh_p = Whh0; whr_p = Whr0; }
    else if (wave == 1) { whh_p = Whh1; whr_p = Whr1; }
    else                { whh_p = Whh2; whr_p = Whr2; }

#pragma unroll
    for (int g = 0; g < 4; ++g) {
        const float sc = (g == 2) ? SC_G : SC_IFO;
        float4 w = *(const float4*)(whh_p + g * 256 + jb);
        whh[g*4+0] = w.x * sc; whh[g*4+1] = w.y * sc;
        whh[g*4+2] = w.z * sc; whh[g*4+3] = w.w * sc;
    }
    {
        float4 w = *(const float4*)(whr_p + jb);
        whr[0] = w.x; whr[1] = w.y; whr[2] = w.z; whr[3] = w.w;
    }

    if (wave == 0) {
#pragma unroll
        for (int g = 0; g < 4; ++g) {
            float4 v = *(const float4*)(Gxb + b * 1024 + g * 256 + jb);
            base[g*4+0] = v.x; base[g*4+1] = v.y; base[g*4+2] = v.z; base[g*4+3] = v.w;
            wih[g*4+0] = 0.f; wih[g*4+1] = 0.f; wih[g*4+2] = 0.f; wih[g*4+3] = 0.f;
        }
    } else {
        const float* bi = (wave == 1) ? bih1 : bih2;
        const float* bh = (wave == 1) ? bhh1 : bhh2;
        const float* wi = (wave == 1) ? Wih1 : Wih2;
#pragma unroll
        for (int g = 0; g < 4; ++g) {
            const float sc = (g == 2) ? SC_G : SC_IFO;
            float4 v1 = *(const float4*)(bi + g * 256 + jb);
            float4 v2 = *(const float4*)(bh + g * 256 + jb);
            float4 v3 = *(const float4*)(wi + g * 256 + jb);
            base[g*4+0] = (v1.x + v2.x) * sc; base[g*4+1] = (v1.y + v2.y) * sc;
            base[g*4+2] = (v1.z + v2.z) * sc; base[g*4+3] = (v1.w + v2.w) * sc;
            wih[g*4+0] = v3.x * sc; wih[g*4+1] = v3.y * sc;
            wih[g*4+2] = v3.z * sc; wih[g*4+3] = v3.w * sc;
        }
    }

    float c4[4] = {0.f, 0.f, 0.f, 0.f};
    float h_state = 0.f;

    for (int e = 0; e < NEPOCH + 2; ++e) {
        __syncthreads();
        const int te = e - wave;                  // this wave's epoch index
        const bool active = (te >= 0) && (te < NEPOCH);

        float pre[U][16];   // h-independent pre-scaled gate contribution

        if (active) {
            if (wave == 0) {
                const float* p = Gf + (size_t)te * U * 1024;
#pragma unroll
                for (int u = 0; u < U; ++u) {
#pragma unroll
                    for (int g = 0; g < 4; ++g) {
                        float4 v = *(const float4*)(p + u * 1024 + g * 256 + jb);
                        pre[u][g*4+0] = v.x + base[g*4+0];
                        pre[u][g*4+1] = v.y + base[g*4+1];
                        pre[u][g*4+2] = v.z + base[g*4+2];
                        pre[u][g*4+3] = v.w + base[g*4+3];
                    }
                }
            } else {
                const int par = (e - 1) & 1;
#pragma unroll
                for (int u = 0; u < U; ++u) {
                    float hin = hbuf[wave - 1][par][u];
#pragma unroll
                    for (int i = 0; i < 16; ++i)
                        pre[u][i] = fmaf(hin, wih[i], base[i]);
                }
            }

#pragma unroll
            for (int u = 0; u < U; ++u) {
                float m[4];
#pragma unroll
                for (int jj = 0; jj < 4; ++jj) {
                    // pre-scaled gate pre-activations -> exp2 directly
                    float gi_s = fmaf(h_state, whh[0*4+jj], pre[u][0*4+jj]);
                    float gf_s = fmaf(h_state, whh[1*4+jj], pre[u][1*4+jj]);
                    float gg_s = fmaf(h_state, whh[2*4+jj], pre[u][2*4+jj]);
                    float go_s = fmaf(h_state, whh[3*4+jj], pre[u][3*4+jj]);
                    float A  = __builtin_amdgcn_exp2f(gi_s);   // e^-gi
                    float Dv = __builtin_amdgcn_exp2f(gf_s);   // e^-gf
                    float Bv = __builtin_amdgcn_exp2f(gg_s);   // e^-2gg
                    float Fv = __builtin_amdgcn_exp2f(go_s);   // e^-go
                    float a1 = 1.f + A, b1 = 1.f + Bv, d1 = 1.f + Dv, f1 = 1.f + Fv;
                    float p1 = a1 * b1;
                    float r1 = __builtin_amdgcn_rcpf(p1 * d1);
                    float si_tg = (1.f - Bv) * d1 * r1;        // sigmoid(gi)*tanh(gg)
                    float sf    = p1 * r1;                     // sigmoid(gf)
                    float c  = fmaf(sf, c4[jj], si_tg);
                    c4[jj] = c;
                    float Cv = __builtin_amdgcn_exp2f(SC_G * c);  // e^-2c
                    float r2 = __builtin_amdgcn_rcpf(f1 * (1.f + Cv));
                    float hr = (1.f - Cv) * r2;                // sigmoid(go)*tanh(c)
                    m[jj] = hr * whr[jj];
                }
                float contrib = (m[0] + m[1]) + (m[2] + m[3]);
                float tot = wave_allreduce(contrib);
                h_state = tot;
                if (lane == 0) hbuf[wave][e & 1][u] = tot;
                if (wave == 2 && lane == 0)
                    out[(size_t)b * NF + te * U + u] = tot;
            }
        }
    }
}

// ---------------------------------------------------------------------------
extern "C" void kernel_launch(void* const* d_in, const int* in_sizes, int n_in,
                              void* d_out, int out_size, void* d_ws, size_t ws_size,
                              hipStream_t stream)
{
    const float* x    = (const float*)d_in[0];
    const float* f    = (const float*)d_in[1];
    const float* Wih0 = (const float*)d_in[2];
    const float* Whh0 = (const float*)d_in[3];
    const float* bih0 = (const float*)d_in[4];
    const float* bhh0 = (const float*)d_in[5];
    const float* Whr0 = (const float*)d_in[6];
    const float* Wih1 = (const float*)d_in[7];
    const float* Whh1 = (const float*)d_in[8];
    const float* bih1 = (const float*)d_in[9];
    const float* bhh1 = (const float*)d_in[10];
    const float* Whr1 = (const float*)d_in[11];
    const float* Wih2 = (const float*)d_in[12];
    const float* Whh2 = (const float*)d_in[13];
    const float* bih2 = (const float*)d_in[14];
    const float* bhh2 = (const float*)d_in[15];
    const float* Whr2 = (const float*)d_in[16];
    float* out = (float*)d_out;

    float* Gf  = (float*)d_ws;                       // NF * 1024 floats (4.1 MB)
    float* Gxb = Gf + (size_t)NF * 1024;             // 64 * 1024 floats

    gf_kernel<<<143, 1024, 0, stream>>>(f, Wih0, Gf);
    gxb_kernel<<<64, 1024, 0, stream>>>(x, Wih0, bih0, bhh0, Gxb);
    lstm_pipeline<<<64, 192, 0, stream>>>(Gf, Gxb, Whh0, Whr0,
                                          Wih1, Whh1, bih1, bhh1, Whr1,
                                          Wih2, Whh2, bih2, bhh2, Whr2,
                                          out);
}